// Round 5
// baseline (982.465 us; speedup 1.0000x reference)
//
#include <hip/hip_runtime.h>

// Problem constants (fixed by the reference):
#define T_DATA 100000
#define E_NO   1000
#define SUB    20
#define TSYN   201
#define PITCH  521   // LDS row pitch for conv tiles: 456 rows + u>>3 swizzle pad (max swz idx 520), odd mod 32

// ---------------------------------------------------------------------------
// K1: syn[t][s] = sum_e S[t][e] * C[s][e]   (tall-skinny GEMM, both e and i)
// lane = row (line-efficient streaming: the block's 4 waves consume the 4
// float4-quarters of each 64B line of S, so every HBM line is fully used).
// C indexed by wave-uniform (s, j) -> scalar s_loads (K$-served, no VALU).
// ---------------------------------------------------------------------------
__global__ __launch_bounds__(256) void k1_matmul(
    const float* __restrict__ S_e, const float* __restrict__ S_i,
    const float* __restrict__ C_e, const float* __restrict__ C_i,
    float* __restrict__ sy_e, float* __restrict__ sy_i)
{
    const int lane = threadIdx.x & 63;
    // readfirstlane: force wave-uniformity of the e-quarter index so the
    // C loads become s_load_dwordx4 (scalar pipe, K$-cached).
    const int q = __builtin_amdgcn_readfirstlane(threadIdx.x >> 6);
    const int row = blockIdx.x * 64 + lane;
    const float* __restrict__ Sp = blockIdx.y ? S_i : S_e;
    const float* __restrict__ Cp = blockIdx.y ? C_i : C_e;
    float* __restrict__ outp = blockIdx.y ? sy_i : sy_e;

    float acc[SUB];
#pragma unroll
    for (int s = 0; s < SUB; ++s) acc[s] = 0.f;

    if (row < T_DATA) {
        const float* rp = Sp + (size_t)row * E_NO;
        // wave q handles float4-chunks j == q (mod 4); 1000 = 250 * 4 exact.
        for (int j = q; j < 250; j += 4) {
            const float4 sv = *reinterpret_cast<const float4*>(rp + 4 * j);
#pragma unroll
            for (int s = 0; s < SUB; ++s) {
                const float4 c4 = *reinterpret_cast<const float4*>(Cp + s * E_NO + 4 * j);
                acc[s] = fmaf(sv.x, c4.x, acc[s]);
                acc[s] = fmaf(sv.y, c4.y, acc[s]);
                acc[s] = fmaf(sv.z, c4.z, acc[s]);
                acc[s] = fmaf(sv.w, c4.w, acc[s]);
            }
        }
    }

    // cross-wave reduction: pitch 21 (odd) -> lane stride 21 words, 2-way max
    __shared__ float red[3 * 64 * 21];
    if (q > 0) {
#pragma unroll
        for (int s = 0; s < SUB; ++s) red[((q - 1) * 64 + lane) * 21 + s] = acc[s];
    }
    __syncthreads();
    if (q == 0 && row < T_DATA) {
#pragma unroll
        for (int p = 0; p < 3; ++p)
#pragma unroll
            for (int s = 0; s < SUB; ++s) acc[s] += red[(p * 64 + lane) * 21 + s];
        float* op = outp + (size_t)row * SUB;
#pragma unroll
        for (int c = 0; c < 5; ++c) {
            float4 v = make_float4(acc[4 * c], acc[4 * c + 1], acc[4 * c + 2], acc[4 * c + 3]);
            *reinterpret_cast<float4*>(op + 4 * c) = v;
        }
    }
}

// ---------------------------------------------------------------------------
// K2 (fused conv + dendritic epilogue):
//   synin[t][s] = b_e[s]+b_i[s] + sum_k w_e[s][k]*syn_e[t-200+k][s]
//                               + sum_k w_i[s][k]*syn_i[t-200+k][s]
//   Y[t][s]     = synin[t][s] + sum_sp synin[t][sp]*exp(W[sp])*Cden[s][sp]
//   volt[t]     = Y[t][0]*exp(W[0]);  Y written twice (tuple outputs 2 and 3).
//
// Conv phase: 5 waves; wave g owns s-group {4g..4g+3}; lanes = 16 t x 4 s.
// Each thread: 16 consecutive outputs via a 32-register sliding window over k
// -> 1 LDS read per k-step (not per FMA). LDS tile [s][u + u>>3] swizzle makes
// the lane stride (16 -> 18 after swizzle) hit 16 distinct banks (<=2-way).
//
// Epilogue phase REMAPS lanes (thread tid<256 owns one t, all 20 s):
//  - Y-tile row reads: lane stride 21 words (odd) -> 2-way, free
//  - Cden/Wss wave-uniform -> s_load
//  - Y1/Y2 stores: per-thread contiguous float4, fully coalesced.
// Fusion is block-safe: Y[t][.] needs only synin[t][.], all computed in-block.
// ---------------------------------------------------------------------------
__global__ __launch_bounds__(320) void k2_conv_epi(
    const float* __restrict__ sy_e, const float* __restrict__ sy_i,
    const float* __restrict__ w_e, const float* __restrict__ b_e,
    const float* __restrict__ w_i, const float* __restrict__ b_i,
    const float* __restrict__ Cden, const float* __restrict__ Wss,
    float* __restrict__ dout)
{
    __shared__ float A0[SUB * PITCH];   // syn_e tile, 456 staged rows (200 halo + 256)
    __shared__ float A1[SUB * PITCH];   // syn_i tile
    const int tid = threadIdx.x;
    const int tb  = blockIdx.x * 256;

    // ---- stage: 456 rows x 20 s x {e,i} as 4560 float4 loads ----
    for (int m = 0; m < 15; ++m) {
        int idx = tid + 320 * m;
        if (idx >= 4560) break;
        int a   = idx >= 2280;
        int id2 = idx - a * 2280;
        int u   = id2 / 5;
        int c   = id2 - 5 * u;
        int t   = tb - 200 + u;
        float4 v = make_float4(0.f, 0.f, 0.f, 0.f);
        const float* src = a ? sy_i : sy_e;
        if (t >= 0 && t < T_DATA) v = *reinterpret_cast<const float4*>(src + t * SUB + 4 * c);
        float* dst = a ? A1 : A0;
        const int sw = u + (u >> 3);             // swizzled t-index (max 511 < 521)
        dst[(4 * c + 0) * PITCH + sw] = v.x;
        dst[(4 * c + 1) * PITCH + sw] = v.y;
        dst[(4 * c + 2) * PITCH + sw] = v.z;
        dst[(4 * c + 3) * PITCH + sw] = v.w;
    }
    __syncthreads();

    const int lane = tid & 63;
    const int g    = tid >> 6;        // wave id = s-group
    const int t_l  = lane & 15;
    const int s_l  = lane >> 4;
    const int s    = 4 * g + s_l;

    float out[16];
    const float bias = b_e[s] + b_i[s];
#pragma unroll
    for (int i = 0; i < 16; ++i) out[i] = bias;

    // per-lane LDS base: swz(16*t_l) = 18*t_l  (16*t_l % 8 == 0 -> separable)
    const int rb = s * PITCH + 18 * t_l;

#pragma unroll 1
    for (int cv = 0; cv < 2; ++cv) {
        const float* Ap = cv ? A1 : A0;
        const float* wp = (cv ? w_i : w_e) + s * TSYN;
        // window invariant entering chunk c: W0[j] = A[u=16*t_l+16c+j], W1 = +16
        float W0[16], W1[16];
#pragma unroll
        for (int j = 0; j < 16; ++j) W0[j] = Ap[rb + j + (j >> 3)];
#pragma unroll
        for (int j = 0; j < 16; ++j) W1[j] = Ap[rb + 16 + j + ((16 + j) >> 3)];
#pragma unroll 1
        for (int c = 0; c < 12; ++c) {      // 12 full 16-k chunks (k 0..191)
            float wreg[16];
#pragma unroll
            for (int kk = 0; kk < 16; ++kk) wreg[kk] = wp[16 * c + kk];
#pragma unroll
            for (int kk = 0; kk < 16; ++kk) {
                const float wv = wreg[kk];
#pragma unroll
                for (int i = 0; i < 16; ++i) {
                    const int ix = kk + i;                       // 0..30, static
                    const float av = (ix < 16) ? W0[ix] : W1[ix - 16];
                    out[i] = fmaf(wv, av, out[i]);
                }
            }
#pragma unroll
            for (int j = 0; j < 16; ++j) W0[j] = W1[j];          // shift window
            const int co = 16 * c + 32;                          // co % 8 == 0
            const int cb = rb + co + (co >> 3);
            // NOTE c==11 refill reads swz idx up to 520 (< PITCH): in-bounds,
            // values beyond u=455 are provably never consumed.
#pragma unroll
            for (int j = 0; j < 16; ++j) W1[j] = Ap[cb + j + (j >> 3)];
        }
        { // partial chunk: k = 192..200 (kk 0..8), uses W0 + W1[0..7]
            float wreg[9];
#pragma unroll
            for (int kk = 0; kk < 9; ++kk) wreg[kk] = wp[192 + kk];
#pragma unroll
            for (int kk = 0; kk < 9; ++kk) {
                const float wv = wreg[kk];
#pragma unroll
                for (int i = 0; i < 16; ++i) {
                    const int ix = kk + i;
                    const float av = (ix < 16) ? W0[ix] : W1[ix - 16];
                    out[i] = fmaf(wv, av, out[i]);
                }
            }
        }
    }

    // ---- epilogue: exchange synin through LDS (reuse A0 footprint) ----
    __syncthreads();                    // all conv reads of A0/A1 done
    float* Yt = A0;                     // [256][21]: 5376 floats < 10420, fits
#pragma unroll
    for (int i = 0; i < 16; ++i) Yt[(16 * t_l + i) * 21 + s] = out[i];
    __syncthreads();

    if (tid < 256) {
        const int t = tb + tid;
        if (t < T_DATA) {
            float* __restrict__ volt = dout;
            float* __restrict__ Y1 = dout + T_DATA;
            float* __restrict__ Y2 = dout + T_DATA + (size_t)T_DATA * SUB;
            // row = synin[t][.], u = row * exp(W)   (lane stride 21: conflict-free)
            float row[SUB], uu[SUB];
#pragma unroll
            for (int sp = 0; sp < SUB; ++sp) {
                const float r = Yt[tid * 21 + sp];
                row[sp] = r;
                uu[sp]  = r * expf(Wss[sp]);         // Wss uniform -> s_load
            }
            float y[SUB];
#pragma unroll
            for (int s2 = 0; s2 < SUB; ++s2) {
                float a2 = row[s2];
#pragma unroll
                for (int sp = 0; sp < SUB; ++sp)
                    a2 = fmaf(Cden[s2 * SUB + sp], uu[sp], a2);  // uniform -> s_load
                y[s2] = a2;
            }
            float* o1 = Y1 + (size_t)t * SUB;
            float* o2 = Y2 + (size_t)t * SUB;
#pragma unroll
            for (int c = 0; c < 5; ++c) {
                float4 v = make_float4(y[4 * c], y[4 * c + 1], y[4 * c + 2], y[4 * c + 3]);
                *reinterpret_cast<float4*>(o1 + 4 * c) = v;      // coalesced
                *reinterpret_cast<float4*>(o2 + 4 * c) = v;
            }
            volt[t] = y[0] * expf(Wss[0]);
        }
    }
}

// ---------------------------------------------------------------------------
extern "C" void kernel_launch(void* const* d_in, const int* in_sizes, int n_in,
                              void* d_out, int out_size, void* d_ws, size_t ws_size,
                              hipStream_t stream)
{
    const float* S_e  = (const float*)d_in[0];
    const float* S_i  = (const float*)d_in[1];
    const float* C_e  = (const float*)d_in[2];
    const float* C_i  = (const float*)d_in[3];
    const float* Cden = (const float*)d_in[4];
    const float* w_e  = (const float*)d_in[5];
    const float* b_e  = (const float*)d_in[6];
    const float* w_i  = (const float*)d_in[7];
    const float* b_i  = (const float*)d_in[8];
    const float* Wss  = (const float*)d_in[9];
    float* out  = (float*)d_out;
    float* sy_e = (float*)d_ws;                      // [T][20] fp32, 8 MB
    float* sy_i = sy_e + (size_t)T_DATA * SUB;       // 8 MB (needs ws >= 16 MB)

    // K1: syn_e / syn_i  (blockIdx.y selects matrix); 1563*64 = 100032 rows
    dim3 g1(1563, 2);
    k1_matmul<<<g1, 256, 0, stream>>>(S_e, S_i, C_e, C_i, sy_e, sy_i);
    // K2: causal depthwise conv + bias + dendritic hop + voltage, fused
    k2_conv_epi<<<391, 320, 0, stream>>>(sy_e, sy_i, w_e, b_e, w_i, b_i,
                                         Cden, Wss, out);
}